// Round 11
// baseline (673.806 us; speedup 1.0000x reference)
//
#include <hip/hip_runtime.h>
#include <stdint.h>

#define MM 1024
#define NN 1024
#define DD 64
#define PP 4096
#define HH 16
#define LL 5120   // P + M
#define SHC 12.0f

typedef float  f32x4  __attribute__((ext_vector_type(4)));
typedef short  s16x8  __attribute__((ext_vector_type(8)));
typedef short  s16x4  __attribute__((ext_vector_type(4)));
typedef __bf16 bf16x8 __attribute__((ext_vector_type(8)));

static __device__ __forceinline__ unsigned short f2bf(float f) {
    unsigned u = __float_as_uint(f);
    u += 0x7FFFu + ((u >> 16) & 1u);   // RNE (no NaNs in this workload)
    return (unsigned short)(u >> 16);
}
static __device__ __forceinline__ float bf2f(unsigned short h) {
    return __uint_as_float(((unsigned)h) << 16);
}
static __device__ __forceinline__ f32x4 mfma16(s16x8 a, s16x8 b, f32x4 c) {
    return __builtin_amdgcn_mfma_f32_16x16x32_bf16(
        __builtin_bit_cast(bf16x8, a), __builtin_bit_cast(bf16x8, b), c, 0, 0, 0);
}

// ---------------- prep: cast X -> (Xh, Xl) bf16 split; cast cache_K into K_all[h][0..P-1][d]
__global__ void k_prep(const float* __restrict__ X, const float* __restrict__ cK,
                       unsigned short* __restrict__ Xh, unsigned short* __restrict__ Xl,
                       unsigned short* __restrict__ Kall) {
    const int nX4 = (MM * NN) / 4;        // 262144
    const int nK4 = (HH * PP * DD) / 4;   // 1048576
    int stride = gridDim.x * blockDim.x;
    for (int i = blockIdx.x * blockDim.x + threadIdx.x; i < nX4 + nK4; i += stride) {
        if (i < nX4) {
            f32x4 v = reinterpret_cast<const f32x4*>(X)[i];
            s16x4 h, l;
            for (int j = 0; j < 4; ++j) {
                float f = v[j];
                unsigned short hb = f2bf(f);
                h[j] = (short)hb;
                l[j] = (short)f2bf(f - bf2f(hb));
            }
            reinterpret_cast<s16x4*>(Xh)[i] = h;
            reinterpret_cast<s16x4*>(Xl)[i] = l;
        } else {
            int j = i - nX4;
            f32x4 v = reinterpret_cast<const f32x4*>(cK)[j];
            s16x4 h;
            for (int jj = 0; jj < 4; ++jj) h[jj] = (short)f2bf(v[jj]);
            int e = j * 4;
            int hh = e >> 18;              // P*D = 262144 = 2^18
            int rem = e & 262143;
            int64_t de = (int64_t)hh * (LL * DD) + rem;
            *reinterpret_cast<s16x4*>(Kall + de) = h;
        }
    }
}

// ---------------- transpose-cast W[k][n] -> WT[n][k] bf16 hi/lo
__global__ void k_transW(const float* __restrict__ Wq, const float* __restrict__ Wk,
                         const float* __restrict__ Wv,
                         unsigned short* __restrict__ WhT, unsigned short* __restrict__ WlT) {
    __shared__ float t[64][68];
    int z = blockIdx.z;
    const float* W = (z == 0) ? Wq : ((z == 1) ? Wk : Wv);
    int n0 = blockIdx.x * 64, k0 = blockIdx.y * 64;
    int tc = threadIdx.x & 15, tr = threadIdx.x >> 4;
    for (int i = 0; i < 4; ++i) {
        int r = tr + i * 16;
        f32x4 v = *reinterpret_cast<const f32x4*>(W + (int64_t)(k0 + r) * NN + n0 + tc * 4);
        t[r][tc * 4 + 0] = v[0]; t[r][tc * 4 + 1] = v[1];
        t[r][tc * 4 + 2] = v[2]; t[r][tc * 4 + 3] = v[3];
    }
    __syncthreads();
    int64_t zoff = (int64_t)z * MM * NN;
    for (int i = 0; i < 4; ++i) {
        int rr = tr + i * 16;
        s16x4 h, l;
        for (int j = 0; j < 4; ++j) {
            float f = t[tc * 4 + j][rr];
            unsigned short hb = f2bf(f);
            h[j] = (short)hb;
            l[j] = (short)f2bf(f - bf2f(hb));
        }
        *reinterpret_cast<s16x4*>(WhT + zoff + (int64_t)(n0 + rr) * NN + k0 + tc * 4) = h;
        *reinterpret_cast<s16x4*>(WlT + zoff + (int64_t)(n0 + rr) * NN + k0 + tc * 4) = l;
    }
}

// ---------------- projection GEMM: C = Xh*Wh + Xh*Wl + Xl*Wh (split-bf16, ~f32 accurate)
__launch_bounds__(256, 4)
__global__ void k_gemm(const unsigned short* __restrict__ Xh, const unsigned short* __restrict__ Xl,
                       const unsigned short* __restrict__ WhT, const unsigned short* __restrict__ WlT,
                       unsigned short* __restrict__ Qh, unsigned short* __restrict__ Ql,
                       unsigned short* __restrict__ Kall, unsigned short* __restrict__ Vproj) {
    __shared__ unsigned short sb[2 * 64 * 72];
    unsigned short* As = sb;
    unsigned short* Bs = sb + 64 * 72;
    int z = blockIdx.z;
    int n0 = blockIdx.x * 64, m0 = blockIdx.y * 64;
    int tid = threadIdx.x, lane = tid & 63, wave = tid >> 6;
    int lrow = lane & 15, lgrp = lane >> 4;
    int wm = (wave >> 1) * 32, wn = (wave & 1) * 32;
    f32x4 acc[2][2] = {};
    for (int seg = 0; seg < 3; ++seg) {
        const unsigned short* Asrc = (seg == 2) ? Xl : Xh;
        const unsigned short* Bsrc = ((seg == 1) ? WlT : WhT) + (int64_t)z * MM * NN;
        for (int kt = 0; kt < 16; ++kt) {
            int kb = kt * 64;
            for (int i = 0; i < 2; ++i) {
                int idx = i * 256 + tid;
                int r = idx >> 3, c8 = (idx & 7) * 8;
                *reinterpret_cast<s16x8*>(&As[r * 72 + c8]) =
                    *reinterpret_cast<const s16x8*>(Asrc + (int64_t)(m0 + r) * NN + kb + c8);
                *reinterpret_cast<s16x8*>(&Bs[r * 72 + c8]) =
                    *reinterpret_cast<const s16x8*>(Bsrc + (int64_t)(n0 + r) * NN + kb + c8);
            }
            __syncthreads();
            for (int ks = 0; ks < 2; ++ks) {
                s16x8 af[2], bfr[2];
                for (int f = 0; f < 2; ++f)
                    af[f] = *reinterpret_cast<const s16x8*>(&As[(wm + f * 16 + lrow) * 72 + ks * 32 + lgrp * 8]);
                for (int f = 0; f < 2; ++f)
                    bfr[f] = *reinterpret_cast<const s16x8*>(&Bs[(wn + f * 16 + lrow) * 72 + ks * 32 + lgrp * 8]);
                for (int i = 0; i < 2; ++i)
                    for (int j = 0; j < 2; ++j)
                        acc[i][j] = mfma16(af[i], bfr[j], acc[i][j]);
            }
            __syncthreads();
        }
    }
    unsigned short* Cs = sb;
    auto stageC = [&](int lo) {
        for (int i = 0; i < 2; ++i)
            for (int j = 0; j < 2; ++j)
                for (int r = 0; r < 4; ++r) {
                    float v = acc[i][j][r];
                    unsigned short hv = f2bf(v);
                    if (lo) hv = f2bf(v - bf2f(hv));
                    Cs[(wm + i * 16 + lgrp * 4 + r) * 72 + wn + j * 16 + lrow] = hv;
                }
    };
    auto writeC = [&](unsigned short* dst, int kmode) {
        for (int i = 0; i < 2; ++i) {
            int idx = i * 256 + tid;
            int r = idx >> 3, c8 = (idx & 7) * 8;
            s16x8 v = *reinterpret_cast<const s16x8*>(&Cs[r * 72 + c8]);
            int gm = m0 + r, gn = n0 + c8;
            if (kmode) {
                int hh = gn >> 6, d = gn & 63;
                *reinterpret_cast<s16x8*>(dst + ((int64_t)hh * LL + PP + gm) * DD + d) = v;
            } else {
                *reinterpret_cast<s16x8*>(dst + (int64_t)gm * NN + gn) = v;
            }
        }
    };
    __syncthreads();
    if (z == 0) {
        stageC(0); __syncthreads(); writeC(Qh, 0);
        __syncthreads(); stageC(1); __syncthreads(); writeC(Ql, 0);
    } else if (z == 1) {
        stageC(0); __syncthreads(); writeC(Kall, 1);
    } else {
        stageC(0); __syncthreads(); writeC(Vproj, 0);
    }
}

// ---------------- V transpose: cache_V (f32) + Vproj (bf16) -> VT[h][d][l] bf16
__global__ void k_transV(const float* __restrict__ cV, const unsigned short* __restrict__ Vproj,
                         unsigned short* __restrict__ VT) {
    __shared__ unsigned short Ts[64][72];
    int b = blockIdx.x;
    int hh = b / 80, lt = b % 80;
    int l0 = lt * 64;
    int tid = threadIdx.x;
    if (l0 < PP) {
        for (int i = 0; i < 4; ++i) {
            int idx = i * 256 + tid;
            int r = idx >> 4, c4 = (idx & 15) * 4;
            f32x4 v = *reinterpret_cast<const f32x4*>(cV + ((int64_t)hh * PP + l0 + r) * DD + c4);
            s16x4 o;
            for (int j = 0; j < 4; ++j) o[j] = (short)f2bf(v[j]);
            *reinterpret_cast<s16x4*>(&Ts[r][c4]) = o;
        }
    } else {
        for (int i = 0; i < 2; ++i) {
            int idx = i * 256 + tid;
            int r = idx >> 3, c8 = (idx & 7) * 8;
            *reinterpret_cast<s16x8*>(&Ts[r][c8]) =
                *reinterpret_cast<const s16x8*>(Vproj + (int64_t)(l0 - PP + r) * NN + hh * DD + c8);
        }
    }
    __syncthreads();
    for (int i = 0; i < 2; ++i) {
        int idx = i * 256 + tid;
        int d = idx >> 3, l8 = (idx & 7) * 8;
        s16x8 v;
        for (int j = 0; j < 8; ++j) v[j] = (short)Ts[l8 + j][d];
        *reinterpret_cast<s16x8*>(VT + ((int64_t)hh * DD + d) * LL + l0 + l8) = v;
    }
}

// ---------------- fused attention, wave-local barrier-free, VMEM-queue-ordered:
// within a chunk, ALL loads (V early, rolling noise prefetch) issue BEFORE the W/P
// stores, so no s_waitcnt for a load ever has to drain stores (in-order vmcnt).
// 1-D grid 1024, XCD-swizzled: xcd=id&7 owns heads {2*xcd, 2*xcd+1}; 16 q-rows per block
__launch_bounds__(256, 4)
__global__ void k_attn2(const unsigned short* __restrict__ Qh, const unsigned short* __restrict__ Ql,
                        const unsigned short* __restrict__ Kall, const unsigned short* __restrict__ VT,
                        const float* __restrict__ noise,
                        float* __restrict__ outO, float* __restrict__ outW, float* __restrict__ outP) {
    // per-wave: scf[16][68] f32 (4352 B) + wls[16][72] bf16 (2304 B) = 6656 B; x4 waves = 26624 B
    __shared__ __align__(16) char smem[26624];
    __shared__ float sred[4][16][2];             // per-wave row-sum partials
    __shared__ float siwp[16][2];                // 1/Sw, 1/Sp per row

    int id = blockIdx.x;
    int xcd = id & 7, j = id >> 3;               // j in [0,128)
    int hh = xcd * 2 + (j >> 6);
    int mt = j & 63;
    int m0 = mt * 16;
    int tid = threadIdx.x, lane = tid & 63, wave = tid >> 6;
    int lrow = lane & 15, lgrp = lane >> 4;

    float (*scf)[68] = (float(*)[68])(smem + wave * 6656);
    unsigned short (*wls)[72] = (unsigned short(*)[72])(smem + wave * 6656 + 4352);

    s16x8 aqh[2], aql[2];
    for (int ks = 0; ks < 2; ++ks) {
        int64_t off = (int64_t)(m0 + lrow) * NN + hh * DD + ks * 32 + lgrp * 8;
        aqh[ks] = *reinterpret_cast<const s16x8*>(Qh + off);
        aql[ks] = *reinterpret_cast<const s16x8*>(Ql + off);
    }
    const unsigned short* Kh = Kall + (int64_t)hh * LL * DD;
    const unsigned short* Vh = VT + (int64_t)hh * DD * LL;
    const float* nzw = noise + ((int64_t)hh * MM + m0) * LL;   // block row base
    float* Wb = outW + ((int64_t)hh * MM + m0) * LL;
    float* Pb = outP + ((int64_t)hh * MM + m0) * LL;

    // ---- pass A: barrier-free row sums; rolling one-chunk-ahead noise prefetch
    float SwR[4] = {}, SpR[4] = {};
    f32x4 nvA[4];
    for (int rp = 0; rp < 4; ++rp)
        nvA[rp] = *reinterpret_cast<const f32x4*>(
            nzw + (int64_t)(rp * 4 + lgrp) * LL + wave * 64 + lrow * 4);
    for (int c = 0; c < 20; ++c) {
        int lb = c * 256 + wave * 64;
        f32x4 sacc[4] = {};
        for (int ks = 0; ks < 2; ++ks)
            for (int lf = 0; lf < 4; ++lf) {
                s16x8 bk = *reinterpret_cast<const s16x8*>(
                    Kh + (int64_t)(lb + lf * 16 + lrow) * DD + ks * 32 + lgrp * 8);
                sacc[lf] = mfma16(aqh[ks], bk, sacc[lf]);
                sacc[lf] = mfma16(aql[ks], bk, sacc[lf]);
            }
        for (int lf = 0; lf < 4; ++lf)
            for (int r = 0; r < 4; ++r)
                scf[lgrp * 4 + r][lf * 16 + lrow] = sacc[lf][r];
        f32x4 nvN[4];
        if (c < 19)
            for (int rp = 0; rp < 4; ++rp)
                nvN[rp] = *reinterpret_cast<const f32x4*>(
                    nzw + (int64_t)(rp * 4 + lgrp) * LL + lb + 256 + lrow * 4);
        for (int rp = 0; rp < 4; ++rp) {
            f32x4 s = *reinterpret_cast<const f32x4*>(&scf[rp * 4 + lgrp][lrow * 4]);
            for (int jj = 0; jj < 4; ++jj) {
                SwR[rp] += __expf(s[jj] - SHC);
                SpR[rp] += __expf((s[jj] + nvA[rp][jj]) * (1.f / 1.5f) - SHC);
            }
        }
        if (c < 19)
            for (int rp = 0; rp < 4; ++rp) nvA[rp] = nvN[rp];
    }
    for (int rp = 0; rp < 4; ++rp)
        for (int d = 1; d < 16; d <<= 1) {
            SwR[rp] += __shfl_xor(SwR[rp], d, 64);
            SpR[rp] += __shfl_xor(SpR[rp], d, 64);
        }
    if (lrow == 0)
        for (int rp = 0; rp < 4; ++rp) {
            sred[wave][rp * 4 + lgrp][0] = SwR[rp];
            sred[wave][rp * 4 + lgrp][1] = SpR[rp];
        }
    __syncthreads();
    if (tid < 32) {
        int row = tid >> 1, ty = tid & 1;
        float S = sred[0][row][ty] + sred[1][row][ty] + sred[2][row][ty] + sred[3][row][ty];
        siwp[row][ty] = 1.f / S;
    }
    __syncthreads();
    float iwr[4], ipr[4];
    for (int rp = 0; rp < 4; ++rp) {
        iwr[rp] = siwp[rp * 4 + lgrp][0];
        ipr[rp] = siwp[rp * 4 + lgrp][1];
    }

    // ---- pass B (reverse order): V loaded at chunk top, noise rolling prefetch,
    //      stores issued LAST so no load ever waits behind them
    f32x4 oacc[4] = {};
    f32x4 nvC[4];
    for (int rp = 0; rp < 4; ++rp)
        nvC[rp] = *reinterpret_cast<const f32x4*>(
            nzw + (int64_t)(rp * 4 + lgrp) * LL + 19 * 256 + wave * 64 + lrow * 4);
    for (int c = 19; c >= 0; --c) {
        int lb = c * 256 + wave * 64;
        // V for this chunk, into registers, BEFORE any store of this chunk
        s16x8 vv[2][4];
        for (int ks = 0; ks < 2; ++ks)
            for (int df = 0; df < 4; ++df)
                vv[ks][df] = *reinterpret_cast<const s16x8*>(
                    Vh + (int64_t)(df * 16 + lrow) * LL + lb + ks * 32 + lgrp * 8);
        f32x4 sacc[4] = {};
        for (int ks = 0; ks < 2; ++ks)
            for (int lf = 0; lf < 4; ++lf) {
                s16x8 bk = *reinterpret_cast<const s16x8*>(
                    Kh + (int64_t)(lb + lf * 16 + lrow) * DD + ks * 32 + lgrp * 8);
                sacc[lf] = mfma16(aqh[ks], bk, sacc[lf]);
                sacc[lf] = mfma16(aql[ks], bk, sacc[lf]);
            }
        for (int lf = 0; lf < 4; ++lf)
            for (int r = 0; r < 4; ++r)
                scf[lgrp * 4 + r][lf * 16 + lrow] = sacc[lf][r];
        // prefetch next chunk's noise (still before this chunk's stores)
        f32x4 nvN[4];
        if (c > 0)
            for (int rp = 0; rp < 4; ++rp)
                nvN[rp] = *reinterpret_cast<const f32x4*>(
                    nzw + (int64_t)(rp * 4 + lgrp) * LL + lb - 256 + lrow * 4);
        // emit (uses registers nvC + wave-local scf), stores go last in the queue
        for (int rp = 0; rp < 4; ++rp) {
            int row = rp * 4 + lgrp;
            f32x4 s = *reinterpret_cast<const f32x4*>(&scf[row][lrow * 4]);
            f32x4 wv, pv;
            for (int jj = 0; jj < 4; ++jj) {
                wv[jj] = __expf(s[jj] - SHC) * iwr[rp];
                pv[jj] = __expf((s[jj] + nvC[rp][jj]) * (1.f / 1.5f) - SHC) * ipr[rp];
            }
            *reinterpret_cast<f32x4*>(Wb + (int64_t)row * LL + lb + lrow * 4) = wv;
            *reinterpret_cast<f32x4*>(Pb + (int64_t)row * LL + lb + lrow * 4) = pv;
            s16x4 pk;
            for (int jj = 0; jj < 4; ++jj) pk[jj] = (short)f2bf(wv[jj]);
            *reinterpret_cast<s16x4*>(&wls[row][lrow * 4]) = pk;
        }
        // PV entirely from registers (vv) + wave-local LDS (wls): no VMEM wait after stores
        for (int ks = 0; ks < 2; ++ks) {
            s16x8 bw = *reinterpret_cast<const s16x8*>(&wls[lrow][ks * 32 + lgrp * 8]);
            for (int df = 0; df < 4; ++df)
                oacc[df] = mfma16(vv[ks][df], bw, oacc[df]);
        }
        if (c > 0)
            for (int rp = 0; rp < 4; ++rp) nvC[rp] = nvN[rp];
    }
    __syncthreads();
    // ---- cross-wave O^T reduce via LDS (aliases smem), direct O write (already normalized)
    float* ored = (float*)smem;                  // [4][64][17] f32 = 17408 B <= 26624
    for (int df = 0; df < 4; ++df)
        for (int r = 0; r < 4; ++r)
            ored[(wave * 64 + df * 16 + lgrp * 4 + r) * 17 + lrow] = oacc[df][r];
    __syncthreads();
    for (int i = 0; i < 4; ++i) {
        int idx = i * 256 + tid;
        int m = idx >> 6, d = idx & 63;
        float v = ored[d * 17 + m] + ored[(64 + d) * 17 + m] +
                  ored[(128 + d) * 17 + m] + ored[(192 + d) * 17 + m];
        outO[(int64_t)(m0 + m) * NN + hh * DD + d] = v;
    }
}

extern "C" void kernel_launch(void* const* d_in, const int* in_sizes, int n_in,
                              void* d_out, int out_size, void* d_ws, size_t ws_size,
                              hipStream_t stream) {
    const float* X  = (const float*)d_in[0];
    const float* Wq = (const float*)d_in[1];
    const float* Wk = (const float*)d_in[2];
    const float* Wv = (const float*)d_in[3];
    const float* cK = (const float*)d_in[4];
    const float* cV = (const float*)d_in[5];
    const float* nz = (const float*)d_in[6];

    char* ws = (char*)d_ws;
    const int64_t U = 1 << 21;   // 2 MB units
    unsigned short* Xh    = (unsigned short*)(ws + 0 * U);
    unsigned short* Xl    = (unsigned short*)(ws + 1 * U);
    unsigned short* WhT   = (unsigned short*)(ws + 2 * U);   // 3 units
    unsigned short* WlT   = (unsigned short*)(ws + 5 * U);   // 3 units
    unsigned short* Qh    = (unsigned short*)(ws + 8 * U);
    unsigned short* Ql    = (unsigned short*)(ws + 9 * U);
    unsigned short* Kall  = (unsigned short*)(ws + 10 * U);  // 5 units
    unsigned short* Vproj = (unsigned short*)(ws + 15 * U);
    unsigned short* VT    = (unsigned short*)(ws + 16 * U);  // 5 units

    float* outO = (float*)d_out;
    float* outW = outO + (int64_t)MM * NN;
    float* outP = outW + (int64_t)HH * MM * LL;

    k_prep<<<2048, 256, 0, stream>>>(X, cK, Xh, Xl, Kall);
    k_transW<<<dim3(16, 16, 3), 256, 0, stream>>>(Wq, Wk, Wv, WhT, WlT);
    k_gemm<<<dim3(16, 16, 3), 256, 0, stream>>>(Xh, Xl, WhT, WlT, Qh, Ql, Kall, Vproj);
    k_transV<<<1280, 256, 0, stream>>>(cV, Vproj, VT);
    k_attn2<<<1024, 256, 0, stream>>>(Qh, Ql, Kall, VT, nz, outO, outW, outP);
}

// Round 12
// 499.985 us; speedup vs baseline: 1.3477x; 1.3477x over previous
//
#include <hip/hip_runtime.h>
#include <stdint.h>

#define MM 1024
#define NN 1024
#define DD 64
#define PP 4096
#define HH 16
#define LL 5120   // P + M
#define SHC 12.0f

typedef float  f32x4  __attribute__((ext_vector_type(4)));
typedef short  s16x8  __attribute__((ext_vector_type(8)));
typedef short  s16x4  __attribute__((ext_vector_type(4)));
typedef __bf16 bf16x8 __attribute__((ext_vector_type(8)));

static __device__ __forceinline__ unsigned short f2bf(float f) {
    unsigned u = __float_as_uint(f);
    u += 0x7FFFu + ((u >> 16) & 1u);   // RNE (no NaNs in this workload)
    return (unsigned short)(u >> 16);
}
static __device__ __forceinline__ float bf2f(unsigned short h) {
    return __uint_as_float(((unsigned)h) << 16);
}
static __device__ __forceinline__ f32x4 mfma16(s16x8 a, s16x8 b, f32x4 c) {
    return __builtin_amdgcn_mfma_f32_16x16x32_bf16(
        __builtin_bit_cast(bf16x8, a), __builtin_bit_cast(bf16x8, b), c, 0, 0, 0);
}

// ---------------- prep: cast X -> (Xh, Xl) bf16 split; cast cache_K into K_all[h][0..P-1][d]
__global__ void k_prep(const float* __restrict__ X, const float* __restrict__ cK,
                       unsigned short* __restrict__ Xh, unsigned short* __restrict__ Xl,
                       unsigned short* __restrict__ Kall) {
    const int nX4 = (MM * NN) / 4;        // 262144
    const int nK4 = (HH * PP * DD) / 4;   // 1048576
    int stride = gridDim.x * blockDim.x;
    for (int i = blockIdx.x * blockDim.x + threadIdx.x; i < nX4 + nK4; i += stride) {
        if (i < nX4) {
            f32x4 v = reinterpret_cast<const f32x4*>(X)[i];
            s16x4 h, l;
            for (int j = 0; j < 4; ++j) {
                float f = v[j];
                unsigned short hb = f2bf(f);
                h[j] = (short)hb;
                l[j] = (short)f2bf(f - bf2f(hb));
            }
            reinterpret_cast<s16x4*>(Xh)[i] = h;
            reinterpret_cast<s16x4*>(Xl)[i] = l;
        } else {
            int j = i - nX4;
            f32x4 v = reinterpret_cast<const f32x4*>(cK)[j];
            s16x4 h;
            for (int jj = 0; jj < 4; ++jj) h[jj] = (short)f2bf(v[jj]);
            int e = j * 4;
            int hh = e >> 18;              // P*D = 262144 = 2^18
            int rem = e & 262143;
            int64_t de = (int64_t)hh * (LL * DD) + rem;
            *reinterpret_cast<s16x4*>(Kall + de) = h;
        }
    }
}

// ---------------- transpose-cast W[k][n] -> WT[n][k] bf16 hi/lo
__global__ void k_transW(const float* __restrict__ Wq, const float* __restrict__ Wk,
                         const float* __restrict__ Wv,
                         unsigned short* __restrict__ WhT, unsigned short* __restrict__ WlT) {
    __shared__ float t[64][68];
    int z = blockIdx.z;
    const float* W = (z == 0) ? Wq : ((z == 1) ? Wk : Wv);
    int n0 = blockIdx.x * 64, k0 = blockIdx.y * 64;
    int tc = threadIdx.x & 15, tr = threadIdx.x >> 4;
    for (int i = 0; i < 4; ++i) {
        int r = tr + i * 16;
        f32x4 v = *reinterpret_cast<const f32x4*>(W + (int64_t)(k0 + r) * NN + n0 + tc * 4);
        t[r][tc * 4 + 0] = v[0]; t[r][tc * 4 + 1] = v[1];
        t[r][tc * 4 + 2] = v[2]; t[r][tc * 4 + 3] = v[3];
    }
    __syncthreads();
    int64_t zoff = (int64_t)z * MM * NN;
    for (int i = 0; i < 4; ++i) {
        int rr = tr + i * 16;
        s16x4 h, l;
        for (int j = 0; j < 4; ++j) {
            float f = t[tc * 4 + j][rr];
            unsigned short hb = f2bf(f);
            h[j] = (short)hb;
            l[j] = (short)f2bf(f - bf2f(hb));
        }
        *reinterpret_cast<s16x4*>(WhT + zoff + (int64_t)(n0 + rr) * NN + k0 + tc * 4) = h;
        *reinterpret_cast<s16x4*>(WlT + zoff + (int64_t)(n0 + rr) * NN + k0 + tc * 4) = l;
    }
}

// ---------------- projection GEMM: C = Xh*Wh + Xh*Wl + Xl*Wh (split-bf16, ~f32 accurate)
// 64x64 tiles, grid (16,16,3) = 768 blocks (3/CU) for latency hiding
__launch_bounds__(256, 4)
__global__ void k_gemm(const unsigned short* __restrict__ Xh, const unsigned short* __restrict__ Xl,
                       const unsigned short* __restrict__ WhT, const unsigned short* __restrict__ WlT,
                       unsigned short* __restrict__ Qh, unsigned short* __restrict__ Ql,
                       unsigned short* __restrict__ Kall, unsigned short* __restrict__ Vproj) {
    __shared__ unsigned short sb[2 * 64 * 72];
    unsigned short* As = sb;
    unsigned short* Bs = sb + 64 * 72;
    int z = blockIdx.z;
    int n0 = blockIdx.x * 64, m0 = blockIdx.y * 64;
    int tid = threadIdx.x, lane = tid & 63, wave = tid >> 6;
    int lrow = lane & 15, lgrp = lane >> 4;
    int wm = (wave >> 1) * 32, wn = (wave & 1) * 32;
    f32x4 acc[2][2] = {};
    for (int seg = 0; seg < 3; ++seg) {
        const unsigned short* Asrc = (seg == 2) ? Xl : Xh;
        const unsigned short* Bsrc = ((seg == 1) ? WlT : WhT) + (int64_t)z * MM * NN;
        for (int kt = 0; kt < 16; ++kt) {
            int kb = kt * 64;
            for (int i = 0; i < 2; ++i) {
                int idx = i * 256 + tid;
                int r = idx >> 3, c8 = (idx & 7) * 8;
                *reinterpret_cast<s16x8*>(&As[r * 72 + c8]) =
                    *reinterpret_cast<const s16x8*>(Asrc + (int64_t)(m0 + r) * NN + kb + c8);
                *reinterpret_cast<s16x8*>(&Bs[r * 72 + c8]) =
                    *reinterpret_cast<const s16x8*>(Bsrc + (int64_t)(n0 + r) * NN + kb + c8);
            }
            __syncthreads();
            for (int ks = 0; ks < 2; ++ks) {
                s16x8 af[2], bfr[2];
                for (int f = 0; f < 2; ++f)
                    af[f] = *reinterpret_cast<const s16x8*>(&As[(wm + f * 16 + lrow) * 72 + ks * 32 + lgrp * 8]);
                for (int f = 0; f < 2; ++f)
                    bfr[f] = *reinterpret_cast<const s16x8*>(&Bs[(wn + f * 16 + lrow) * 72 + ks * 32 + lgrp * 8]);
                for (int i = 0; i < 2; ++i)
                    for (int j = 0; j < 2; ++j)
                        acc[i][j] = mfma16(af[i], bfr[j], acc[i][j]);
            }
            __syncthreads();
        }
    }
    unsigned short* Cs = sb;   // reuse staging LDS, pitch 72, 64x64 tile
    auto stageC = [&](int lo) {
        for (int i = 0; i < 2; ++i)
            for (int j = 0; j < 2; ++j)
                for (int r = 0; r < 4; ++r) {
                    float v = acc[i][j][r];
                    unsigned short hv = f2bf(v);
                    if (lo) hv = f2bf(v - bf2f(hv));
                    Cs[(wm + i * 16 + lgrp * 4 + r) * 72 + wn + j * 16 + lrow] = hv;
                }
    };
    auto writeC = [&](unsigned short* dst, int kmode) {
        for (int i = 0; i < 2; ++i) {
            int idx = i * 256 + tid;
            int r = idx >> 3, c8 = (idx & 7) * 8;
            s16x8 v = *reinterpret_cast<const s16x8*>(&Cs[r * 72 + c8]);
            int gm = m0 + r, gn = n0 + c8;
            if (kmode) {
                int hh = gn >> 6, d = gn & 63;
                *reinterpret_cast<s16x8*>(dst + ((int64_t)hh * LL + PP + gm) * DD + d) = v;
            } else {
                *reinterpret_cast<s16x8*>(dst + (int64_t)gm * NN + gn) = v;
            }
        }
    };
    __syncthreads();
    if (z == 0) {
        stageC(0); __syncthreads(); writeC(Qh, 0);
        __syncthreads(); stageC(1); __syncthreads(); writeC(Ql, 0);
    } else if (z == 1) {
        stageC(0); __syncthreads(); writeC(Kall, 1);
    } else {
        stageC(0); __syncthreads(); writeC(Vproj, 0);
    }
}

// ---------------- V transpose: cache_V (f32) + Vproj (bf16) -> VT[h][d][l] bf16
__global__ void k_transV(const float* __restrict__ cV, const unsigned short* __restrict__ Vproj,
                         unsigned short* __restrict__ VT) {
    __shared__ unsigned short Ts[64][72];
    int b = blockIdx.x;
    int hh = b / 80, lt = b % 80;
    int l0 = lt * 64;
    int tid = threadIdx.x;
    if (l0 < PP) {
        for (int i = 0; i < 4; ++i) {
            int idx = i * 256 + tid;
            int r = idx >> 4, c4 = (idx & 15) * 4;
            f32x4 v = *reinterpret_cast<const f32x4*>(cV + ((int64_t)hh * PP + l0 + r) * DD + c4);
            s16x4 o;
            for (int j = 0; j < 4; ++j) o[j] = (short)f2bf(v[j]);
            *reinterpret_cast<s16x4*>(&Ts[r][c4]) = o;
        }
    } else {
        for (int i = 0; i < 2; ++i) {
            int idx = i * 256 + tid;
            int r = idx >> 3, c8 = (idx & 7) * 8;
            *reinterpret_cast<s16x8*>(&Ts[r][c8]) =
                *reinterpret_cast<const s16x8*>(Vproj + (int64_t)(l0 - PP + r) * NN + hh * DD + c8);
        }
    }
    __syncthreads();
    for (int i = 0; i < 2; ++i) {
        int idx = i * 256 + tid;
        int d = idx >> 3, l8 = (idx & 7) * 8;
        s16x8 v;
        for (int j = 0; j < 8; ++j) v[j] = (short)Ts[l8 + j][d];
        *reinterpret_cast<s16x8*>(VT + ((int64_t)hh * DD + d) * LL + l0 + l8) = v;
    }
}

// ---------------- fused attention (R6 structure + V-register hoist in pass B)
// 1-D grid 1024, XCD-swizzled: xcd=id&7 owns heads {2*xcd, 2*xcd+1}; 16 q-rows per block
__launch_bounds__(256, 4)
__global__ void k_attn2(const unsigned short* __restrict__ Qh, const unsigned short* __restrict__ Ql,
                        const unsigned short* __restrict__ Kall, const unsigned short* __restrict__ VT,
                        const float* __restrict__ noise,
                        float* __restrict__ outO, float* __restrict__ outW, float* __restrict__ outP) {
    __shared__ float sc[16][272];            // scores staging; aliased as ored at the end
    __shared__ unsigned short wls[16][264];  // bf16 normalized weights for PV

    int id = blockIdx.x;
    int xcd = id & 7, j = id >> 3;           // j in [0,128)
    int hh = xcd * 2 + (j >> 6);
    int mt = j & 63;
    int m0 = mt * 16;
    int tid = threadIdx.x, lane = tid & 63, wave = tid >> 6;
    int lrow = lane & 15, lgrp = lane >> 4;
    int erow = tid >> 4, cb = tid & 15;      // emit: fixed row per thread

    s16x8 aqh[2], aql[2];
    for (int ks = 0; ks < 2; ++ks) {
        int64_t off = (int64_t)(m0 + lrow) * NN + hh * DD + ks * 32 + lgrp * 8;
        aqh[ks] = *reinterpret_cast<const s16x8*>(Qh + off);
        aql[ks] = *reinterpret_cast<const s16x8*>(Ql + off);
    }
    const unsigned short* Kh = Kall + (int64_t)hh * LL * DD;
    const unsigned short* Vh = VT + (int64_t)hh * DD * LL;
    const float* nzr = noise + ((int64_t)hh * MM + m0 + erow) * LL;
    float* Wr = outW + ((int64_t)hh * MM + m0 + erow) * LL;
    float* Pr = outP + ((int64_t)hh * MM + m0 + erow) * LL;

    // ---- pass A: row sums (noise prefetched before QK^T so HBM latency hides under MFMA)
    float Sw = 0.f, Sp = 0.f;
    for (int c = 0; c < 20; ++c) {
        int c0 = c * 256;
        f32x4 nv[4];
        for (int q = 0; q < 4; ++q)
            nv[q] = *reinterpret_cast<const f32x4*>(nzr + c0 + q * 64 + cb * 4);
        {
            f32x4 sacc[4] = {};
            int lb = c0 + wave * 64;
            for (int ks = 0; ks < 2; ++ks)
                for (int lf = 0; lf < 4; ++lf) {
                    s16x8 bk = *reinterpret_cast<const s16x8*>(
                        Kh + (int64_t)(lb + lf * 16 + lrow) * DD + ks * 32 + lgrp * 8);
                    sacc[lf] = mfma16(aqh[ks], bk, sacc[lf]);
                    sacc[lf] = mfma16(aql[ks], bk, sacc[lf]);
                }
            for (int lf = 0; lf < 4; ++lf)
                for (int r = 0; r < 4; ++r)
                    sc[lgrp * 4 + r][wave * 64 + lf * 16 + lrow] = sacc[lf][r];
        }
        __syncthreads();
        for (int q = 0; q < 4; ++q) {
            int col = q * 64 + cb * 4;
            f32x4 s = *reinterpret_cast<const f32x4*>(&sc[erow][col]);
            for (int jj = 0; jj < 4; ++jj) {
                Sw += __expf(s[jj] - SHC);
                Sp += __expf((s[jj] + nv[q][jj]) * (1.f / 1.5f) - SHC);
            }
        }
        __syncthreads();
    }
    for (int d = 1; d < 16; d <<= 1) {
        Sw += __shfl_xor(Sw, d, 64);
        Sp += __shfl_xor(Sp, d, 64);
    }
    float iw = 1.f / Sw, ip = 1.f / Sp;

    // ---- pass B (reverse chunk order for L3 noise-tail reuse): normalized emit + PV
    // V for each chunk is hoisted into registers BEFORE QK^T so the post-barrier PV
    // phase runs entirely from registers + LDS (no exposed V-load latency).
    f32x4 oacc[4] = {};
    for (int c = 19; c >= 0; --c) {
        int c0 = c * 256;
        s16x8 vv[2][4];
        for (int ks = 0; ks < 2; ++ks)
            for (int df = 0; df < 4; ++df)
                vv[ks][df] = *reinterpret_cast<const s16x8*>(
                    Vh + (int64_t)(df * 16 + lrow) * LL + c0 + wave * 64 + ks * 32 + lgrp * 8);
        f32x4 nv[4];
        for (int q = 0; q < 4; ++q)
            nv[q] = *reinterpret_cast<const f32x4*>(nzr + c0 + q * 64 + cb * 4);
        {
            f32x4 sacc[4] = {};
            int lb = c0 + wave * 64;
            for (int ks = 0; ks < 2; ++ks)
                for (int lf = 0; lf < 4; ++lf) {
                    s16x8 bk = *reinterpret_cast<const s16x8*>(
                        Kh + (int64_t)(lb + lf * 16 + lrow) * DD + ks * 32 + lgrp * 8);
                    sacc[lf] = mfma16(aqh[ks], bk, sacc[lf]);
                    sacc[lf] = mfma16(aql[ks], bk, sacc[lf]);
                }
            for (int lf = 0; lf < 4; ++lf)
                for (int r = 0; r < 4; ++r)
                    sc[lgrp * 4 + r][wave * 64 + lf * 16 + lrow] = sacc[lf][r];
        }
        __syncthreads();
        for (int q = 0; q < 4; ++q) {
            int col = q * 64 + cb * 4;
            f32x4 s = *reinterpret_cast<const f32x4*>(&sc[erow][col]);
            f32x4 wv, pv;
            for (int jj = 0; jj < 4; ++jj) {
                wv[jj] = __expf(s[jj] - SHC) * iw;
                pv[jj] = __expf((s[jj] + nv[q][jj]) * (1.f / 1.5f) - SHC) * ip;
            }
            *reinterpret_cast<f32x4*>(Wr + c0 + col) = wv;
            *reinterpret_cast<f32x4*>(Pr + c0 + col) = pv;
            s16x4 pk;
            for (int jj = 0; jj < 4; ++jj) pk[jj] = (short)f2bf(wv[jj]);
            *reinterpret_cast<s16x4*>(&wls[erow][col]) = pk;
        }
        __syncthreads();
        for (int ks = 0; ks < 2; ++ks) {
            int k0 = wave * 64 + ks * 32;
            s16x8 bw = *reinterpret_cast<const s16x8*>(&wls[lrow][k0 + lgrp * 8]);
            for (int df = 0; df < 4; ++df)
                oacc[df] = mfma16(vv[ks][df], bw, oacc[df]);
        }
    }
    __syncthreads();
    // ---- cross-wave O^T reduce via LDS (aliases sc), direct O write (already normalized)
    float* ored = &sc[0][0];   // [4][64][17]
    for (int df = 0; df < 4; ++df)
        for (int r = 0; r < 4; ++r)
            ored[(wave * 64 + df * 16 + lgrp * 4 + r) * 17 + lrow] = oacc[df][r];
    __syncthreads();
    for (int i = 0; i < 4; ++i) {
        int idx = i * 256 + tid;
        int m = idx >> 6, d = idx & 63;
        float v = ored[d * 17 + m] + ored[(64 + d) * 17 + m] +
                  ored[(128 + d) * 17 + m] + ored[(192 + d) * 17 + m];
        outO[(int64_t)(m0 + m) * NN + hh * DD + d] = v;
    }
}

extern "C" void kernel_launch(void* const* d_in, const int* in_sizes, int n_in,
                              void* d_out, int out_size, void* d_ws, size_t ws_size,
                              hipStream_t stream) {
    const float* X  = (const float*)d_in[0];
    const float* Wq = (const float*)d_in[1];
    const float* Wk = (const float*)d_in[2];
    const float* Wv = (const float*)d_in[3];
    const float* cK = (const float*)d_in[4];
    const float* cV = (const float*)d_in[5];
    const float* nz = (const float*)d_in[6];

    char* ws = (char*)d_ws;
    const int64_t U = 1 << 21;   // 2 MB units
    unsigned short* Xh    = (unsigned short*)(ws + 0 * U);
    unsigned short* Xl    = (unsigned short*)(ws + 1 * U);
    unsigned short* WhT   = (unsigned short*)(ws + 2 * U);   // 3 units
    unsigned short* WlT   = (unsigned short*)(ws + 5 * U);   // 3 units
    unsigned short* Qh    = (unsigned short*)(ws + 8 * U);
    unsigned short* Ql    = (unsigned short*)(ws + 9 * U);
    unsigned short* Kall  = (unsigned short*)(ws + 10 * U);  // 5 units
    unsigned short* Vproj = (unsigned short*)(ws + 15 * U);
    unsigned short* VT    = (unsigned short*)(ws + 16 * U);  // 5 units

    float* outO = (float*)d_out;
    float* outW = outO + (int64_t)MM * NN;
    float* outP = outW + (int64_t)HH * MM * LL;

    k_prep<<<2048, 256, 0, stream>>>(X, cK, Xh, Xl, Kall);
    k_transW<<<dim3(16, 16, 3), 256, 0, stream>>>(Wq, Wk, Wv, WhT, WlT);
    k_gemm<<<dim3(16, 16, 3), 256, 0, stream>>>(Xh, Xl, WhT, WlT, Qh, Ql, Kall, Vproj);
    k_transV<<<1280, 256, 0, stream>>>(cV, Vproj, VT);
    k_attn2<<<1024, 256, 0, stream>>>(Qh, Ql, Kall, VT, nz, outO, outW, outP);
}

// Round 13
// 469.375 us; speedup vs baseline: 1.4355x; 1.0652x over previous
//
#include <hip/hip_runtime.h>
#include <stdint.h>

#define MM 1024
#define NN 1024
#define DD 64
#define PP 4096
#define HH 16
#define LL 5120   // P + M
#define SHC 12.0f

typedef float  f32x4  __attribute__((ext_vector_type(4)));
typedef short  s16x8  __attribute__((ext_vector_type(8)));
typedef short  s16x4  __attribute__((ext_vector_type(4)));
typedef __bf16 bf16x8 __attribute__((ext_vector_type(8)));

static __device__ __forceinline__ unsigned short f2bf(float f) {
    unsigned u = __float_as_uint(f);
    u += 0x7FFFu + ((u >> 16) & 1u);   // RNE (no NaNs in this workload)
    return (unsigned short)(u >> 16);
}
static __device__ __forceinline__ float bf2f(unsigned short h) {
    return __uint_as_float(((unsigned)h) << 16);
}
static __device__ __forceinline__ f32x4 mfma16(s16x8 a, s16x8 b, f32x4 c) {
    return __builtin_amdgcn_mfma_f32_16x16x32_bf16(
        __builtin_bit_cast(bf16x8, a), __builtin_bit_cast(bf16x8, b), c, 0, 0, 0);
}

// ---------------- prep: cast X -> (Xh, Xl) bf16 split; cast cache_K into K_all[h][0..P-1][d]
__global__ void k_prep(const float* __restrict__ X, const float* __restrict__ cK,
                       unsigned short* __restrict__ Xh, unsigned short* __restrict__ Xl,
                       unsigned short* __restrict__ Kall) {
    const int nX4 = (MM * NN) / 4;        // 262144
    const int nK4 = (HH * PP * DD) / 4;   // 1048576
    int stride = gridDim.x * blockDim.x;
    for (int i = blockIdx.x * blockDim.x + threadIdx.x; i < nX4 + nK4; i += stride) {
        if (i < nX4) {
            f32x4 v = reinterpret_cast<const f32x4*>(X)[i];
            s16x4 h, l;
            for (int j = 0; j < 4; ++j) {
                float f = v[j];
                unsigned short hb = f2bf(f);
                h[j] = (short)hb;
                l[j] = (short)f2bf(f - bf2f(hb));
            }
            reinterpret_cast<s16x4*>(Xh)[i] = h;
            reinterpret_cast<s16x4*>(Xl)[i] = l;
        } else {
            int j = i - nX4;
            f32x4 v = reinterpret_cast<const f32x4*>(cK)[j];
            s16x4 h;
            for (int jj = 0; jj < 4; ++jj) h[jj] = (short)f2bf(v[jj]);
            int e = j * 4;
            int hh = e >> 18;              // P*D = 262144 = 2^18
            int rem = e & 262143;
            int64_t de = (int64_t)hh * (LL * DD) + rem;
            *reinterpret_cast<s16x4*>(Kall + de) = h;
        }
    }
}

// ---------------- transpose-cast W[k][n] -> WT[n][k] bf16 hi/lo
__global__ void k_transW(const float* __restrict__ Wq, const float* __restrict__ Wk,
                         const float* __restrict__ Wv,
                         unsigned short* __restrict__ WhT, unsigned short* __restrict__ WlT) {
    __shared__ float t[64][68];
    int z = blockIdx.z;
    const float* W = (z == 0) ? Wq : ((z == 1) ? Wk : Wv);
    int n0 = blockIdx.x * 64, k0 = blockIdx.y * 64;
    int tc = threadIdx.x & 15, tr = threadIdx.x >> 4;
    for (int i = 0; i < 4; ++i) {
        int r = tr + i * 16;
        f32x4 v = *reinterpret_cast<const f32x4*>(W + (int64_t)(k0 + r) * NN + n0 + tc * 4);
        t[r][tc * 4 + 0] = v[0]; t[r][tc * 4 + 1] = v[1];
        t[r][tc * 4 + 2] = v[2]; t[r][tc * 4 + 3] = v[3];
    }
    __syncthreads();
    int64_t zoff = (int64_t)z * MM * NN;
    for (int i = 0; i < 4; ++i) {
        int rr = tr + i * 16;
        s16x4 h, l;
        for (int j = 0; j < 4; ++j) {
            float f = t[tc * 4 + j][rr];
            unsigned short hb = f2bf(f);
            h[j] = (short)hb;
            l[j] = (short)f2bf(f - bf2f(hb));
        }
        *reinterpret_cast<s16x4*>(WhT + zoff + (int64_t)(n0 + rr) * NN + k0 + tc * 4) = h;
        *reinterpret_cast<s16x4*>(WlT + zoff + (int64_t)(n0 + rr) * NN + k0 + tc * 4) = l;
    }
}

// ---------------- projection GEMM: C = Xh*Wh + Xh*Wl + Xl*Wh (split-bf16, ~f32 accurate)
// 64x64 tiles, grid (16,16,3) = 768 blocks (3/CU) for latency hiding
__launch_bounds__(256, 4)
__global__ void k_gemm(const unsigned short* __restrict__ Xh, const unsigned short* __restrict__ Xl,
                       const unsigned short* __restrict__ WhT, const unsigned short* __restrict__ WlT,
                       unsigned short* __restrict__ Qh, unsigned short* __restrict__ Ql,
                       unsigned short* __restrict__ Kall, unsigned short* __restrict__ Vproj) {
    __shared__ unsigned short sb[2 * 64 * 72];
    unsigned short* As = sb;
    unsigned short* Bs = sb + 64 * 72;
    int z = blockIdx.z;
    int n0 = blockIdx.x * 64, m0 = blockIdx.y * 64;
    int tid = threadIdx.x, lane = tid & 63, wave = tid >> 6;
    int lrow = lane & 15, lgrp = lane >> 4;
    int wm = (wave >> 1) * 32, wn = (wave & 1) * 32;
    f32x4 acc[2][2] = {};
    for (int seg = 0; seg < 3; ++seg) {
        const unsigned short* Asrc = (seg == 2) ? Xl : Xh;
        const unsigned short* Bsrc = ((seg == 1) ? WlT : WhT) + (int64_t)z * MM * NN;
        for (int kt = 0; kt < 16; ++kt) {
            int kb = kt * 64;
            for (int i = 0; i < 2; ++i) {
                int idx = i * 256 + tid;
                int r = idx >> 3, c8 = (idx & 7) * 8;
                *reinterpret_cast<s16x8*>(&As[r * 72 + c8]) =
                    *reinterpret_cast<const s16x8*>(Asrc + (int64_t)(m0 + r) * NN + kb + c8);
                *reinterpret_cast<s16x8*>(&Bs[r * 72 + c8]) =
                    *reinterpret_cast<const s16x8*>(Bsrc + (int64_t)(n0 + r) * NN + kb + c8);
            }
            __syncthreads();
            for (int ks = 0; ks < 2; ++ks) {
                s16x8 af[2], bfr[2];
                for (int f = 0; f < 2; ++f)
                    af[f] = *reinterpret_cast<const s16x8*>(&As[(wm + f * 16 + lrow) * 72 + ks * 32 + lgrp * 8]);
                for (int f = 0; f < 2; ++f)
                    bfr[f] = *reinterpret_cast<const s16x8*>(&Bs[(wn + f * 16 + lrow) * 72 + ks * 32 + lgrp * 8]);
                for (int i = 0; i < 2; ++i)
                    for (int j = 0; j < 2; ++j)
                        acc[i][j] = mfma16(af[i], bfr[j], acc[i][j]);
            }
            __syncthreads();
        }
    }
    unsigned short* Cs = sb;   // reuse staging LDS, pitch 72, 64x64 tile
    auto stageC = [&](int lo) {
        for (int i = 0; i < 2; ++i)
            for (int j = 0; j < 2; ++j)
                for (int r = 0; r < 4; ++r) {
                    float v = acc[i][j][r];
                    unsigned short hv = f2bf(v);
                    if (lo) hv = f2bf(v - bf2f(hv));
                    Cs[(wm + i * 16 + lgrp * 4 + r) * 72 + wn + j * 16 + lrow] = hv;
                }
    };
    auto writeC = [&](unsigned short* dst, int kmode) {
        for (int i = 0; i < 2; ++i) {
            int idx = i * 256 + tid;
            int r = idx >> 3, c8 = (idx & 7) * 8;
            s16x8 v = *reinterpret_cast<const s16x8*>(&Cs[r * 72 + c8]);
            int gm = m0 + r, gn = n0 + c8;
            if (kmode) {
                int hh = gn >> 6, d = gn & 63;
                *reinterpret_cast<s16x8*>(dst + ((int64_t)hh * LL + PP + gm) * DD + d) = v;
            } else {
                *reinterpret_cast<s16x8*>(dst + (int64_t)gm * NN + gn) = v;
            }
        }
    };
    __syncthreads();
    if (z == 0) {
        stageC(0); __syncthreads(); writeC(Qh, 0);
        __syncthreads(); stageC(1); __syncthreads(); writeC(Ql, 0);
    } else if (z == 1) {
        stageC(0); __syncthreads(); writeC(Kall, 1);
    } else {
        stageC(0); __syncthreads(); writeC(Vproj, 0);
    }
}

// ---------------- V transpose: cache_V (f32) + Vproj (bf16) -> VT[h][d][l] bf16
__global__ void k_transV(const float* __restrict__ cV, const unsigned short* __restrict__ Vproj,
                         unsigned short* __restrict__ VT) {
    __shared__ unsigned short Ts[64][72];
    int b = blockIdx.x;
    int hh = b / 80, lt = b % 80;
    int l0 = lt * 64;
    int tid = threadIdx.x;
    if (l0 < PP) {
        for (int i = 0; i < 4; ++i) {
            int idx = i * 256 + tid;
            int r = idx >> 4, c4 = (idx & 15) * 4;
            f32x4 v = *reinterpret_cast<const f32x4*>(cV + ((int64_t)hh * PP + l0 + r) * DD + c4);
            s16x4 o;
            for (int j = 0; j < 4; ++j) o[j] = (short)f2bf(v[j]);
            *reinterpret_cast<s16x4*>(&Ts[r][c4]) = o;
        }
    } else {
        for (int i = 0; i < 2; ++i) {
            int idx = i * 256 + tid;
            int r = idx >> 3, c8 = (idx & 7) * 8;
            *reinterpret_cast<s16x8*>(&Ts[r][c8]) =
                *reinterpret_cast<const s16x8*>(Vproj + (int64_t)(l0 - PP + r) * NN + hh * DD + c8);
        }
    }
    __syncthreads();
    for (int i = 0; i < 2; ++i) {
        int idx = i * 256 + tid;
        int d = idx >> 3, l8 = (idx & 7) * 8;
        s16x8 v;
        for (int j = 0; j < 8; ++j) v[j] = (short)Ts[l8 + j][d];
        *reinterpret_cast<s16x8*>(VT + ((int64_t)hh * DD + d) * LL + l0 + l8) = v;
    }
}

// ---------------- fused attention (exact R6 structure + setprio around MFMA + NT W/P stores)
// 1-D grid 1024, XCD-swizzled: xcd=id&7 owns heads {2*xcd, 2*xcd+1}; 16 q-rows per block
__launch_bounds__(256, 4)
__global__ void k_attn2(const unsigned short* __restrict__ Qh, const unsigned short* __restrict__ Ql,
                        const unsigned short* __restrict__ Kall, const unsigned short* __restrict__ VT,
                        const float* __restrict__ noise,
                        float* __restrict__ outO, float* __restrict__ outW, float* __restrict__ outP) {
    __shared__ float sc[16][272];            // scores staging; aliased as ored at the end
    __shared__ unsigned short wls[16][264];  // bf16 normalized weights for PV

    int id = blockIdx.x;
    int xcd = id & 7, j = id >> 3;           // j in [0,128)
    int hh = xcd * 2 + (j >> 6);
    int mt = j & 63;
    int m0 = mt * 16;
    int tid = threadIdx.x, lane = tid & 63, wave = tid >> 6;
    int lrow = lane & 15, lgrp = lane >> 4;
    int erow = tid >> 4, cb = tid & 15;      // emit: fixed row per thread

    s16x8 aqh[2], aql[2];
    for (int ks = 0; ks < 2; ++ks) {
        int64_t off = (int64_t)(m0 + lrow) * NN + hh * DD + ks * 32 + lgrp * 8;
        aqh[ks] = *reinterpret_cast<const s16x8*>(Qh + off);
        aql[ks] = *reinterpret_cast<const s16x8*>(Ql + off);
    }
    const unsigned short* Kh = Kall + (int64_t)hh * LL * DD;
    const unsigned short* Vh = VT + (int64_t)hh * DD * LL;
    const float* nzr = noise + ((int64_t)hh * MM + m0 + erow) * LL;
    float* Wr = outW + ((int64_t)hh * MM + m0 + erow) * LL;
    float* Pr = outP + ((int64_t)hh * MM + m0 + erow) * LL;

    // ---- pass A: row sums (noise prefetched before QK^T so HBM latency hides under MFMA)
    float Sw = 0.f, Sp = 0.f;
    for (int c = 0; c < 20; ++c) {
        int c0 = c * 256;
        f32x4 nv[4];
        for (int q = 0; q < 4; ++q)
            nv[q] = *reinterpret_cast<const f32x4*>(nzr + c0 + q * 64 + cb * 4);
        {
            f32x4 sacc[4] = {};
            int lb = c0 + wave * 64;
            __builtin_amdgcn_s_setprio(1);
            for (int ks = 0; ks < 2; ++ks)
                for (int lf = 0; lf < 4; ++lf) {
                    s16x8 bk = *reinterpret_cast<const s16x8*>(
                        Kh + (int64_t)(lb + lf * 16 + lrow) * DD + ks * 32 + lgrp * 8);
                    sacc[lf] = mfma16(aqh[ks], bk, sacc[lf]);
                    sacc[lf] = mfma16(aql[ks], bk, sacc[lf]);
                }
            __builtin_amdgcn_s_setprio(0);
            for (int lf = 0; lf < 4; ++lf)
                for (int r = 0; r < 4; ++r)
                    sc[lgrp * 4 + r][wave * 64 + lf * 16 + lrow] = sacc[lf][r];
        }
        __syncthreads();
        for (int q = 0; q < 4; ++q) {
            int col = q * 64 + cb * 4;
            f32x4 s = *reinterpret_cast<const f32x4*>(&sc[erow][col]);
            for (int jj = 0; jj < 4; ++jj) {
                Sw += __expf(s[jj] - SHC);
                Sp += __expf((s[jj] + nv[q][jj]) * (1.f / 1.5f) - SHC);
            }
        }
        __syncthreads();
    }
    for (int d = 1; d < 16; d <<= 1) {
        Sw += __shfl_xor(Sw, d, 64);
        Sp += __shfl_xor(Sp, d, 64);
    }
    float iw = 1.f / Sw, ip = 1.f / Sp;

    // ---- pass B (reverse chunk order for L3 noise-tail reuse): normalized emit + PV
    f32x4 oacc[4] = {};
    for (int c = 19; c >= 0; --c) {
        int c0 = c * 256;
        f32x4 nv[4];
        for (int q = 0; q < 4; ++q)
            nv[q] = *reinterpret_cast<const f32x4*>(nzr + c0 + q * 64 + cb * 4);
        {
            f32x4 sacc[4] = {};
            int lb = c0 + wave * 64;
            __builtin_amdgcn_s_setprio(1);
            for (int ks = 0; ks < 2; ++ks)
                for (int lf = 0; lf < 4; ++lf) {
                    s16x8 bk = *reinterpret_cast<const s16x8*>(
                        Kh + (int64_t)(lb + lf * 16 + lrow) * DD + ks * 32 + lgrp * 8);
                    sacc[lf] = mfma16(aqh[ks], bk, sacc[lf]);
                    sacc[lf] = mfma16(aql[ks], bk, sacc[lf]);
                }
            __builtin_amdgcn_s_setprio(0);
            for (int lf = 0; lf < 4; ++lf)
                for (int r = 0; r < 4; ++r)
                    sc[lgrp * 4 + r][wave * 64 + lf * 16 + lrow] = sacc[lf][r];
        }
        __syncthreads();
        for (int q = 0; q < 4; ++q) {
            int col = q * 64 + cb * 4;
            f32x4 s = *reinterpret_cast<const f32x4*>(&sc[erow][col]);
            f32x4 wv, pv;
            for (int jj = 0; jj < 4; ++jj) {
                wv[jj] = __expf(s[jj] - SHC) * iw;
                pv[jj] = __expf((s[jj] + nv[q][jj]) * (1.f / 1.5f) - SHC) * ip;
            }
            __builtin_nontemporal_store(wv, reinterpret_cast<f32x4*>(Wr + c0 + col));
            __builtin_nontemporal_store(pv, reinterpret_cast<f32x4*>(Pr + c0 + col));
            s16x4 pk;
            for (int jj = 0; jj < 4; ++jj) pk[jj] = (short)f2bf(wv[jj]);
            *reinterpret_cast<s16x4*>(&wls[erow][col]) = pk;
        }
        __syncthreads();
        __builtin_amdgcn_s_setprio(1);
        for (int ks = 0; ks < 2; ++ks) {
            int k0 = wave * 64 + ks * 32;
            s16x8 bw = *reinterpret_cast<const s16x8*>(&wls[lrow][k0 + lgrp * 8]);
            for (int df = 0; df < 4; ++df) {
                s16x8 av = *reinterpret_cast<const s16x8*>(
                    Vh + (int64_t)(df * 16 + lrow) * LL + c0 + k0 + lgrp * 8);
                oacc[df] = mfma16(av, bw, oacc[df]);
            }
        }
        __builtin_amdgcn_s_setprio(0);
    }
    __syncthreads();
    // ---- cross-wave O^T reduce via LDS (aliases sc), direct O write (already normalized)
    float* ored = &sc[0][0];   // [4][64][17]
    for (int df = 0; df < 4; ++df)
        for (int r = 0; r < 4; ++r)
            ored[(wave * 64 + df * 16 + lgrp * 4 + r) * 17 + lrow] = oacc[df][r];
    __syncthreads();
    for (int i = 0; i < 4; ++i) {
        int idx = i * 256 + tid;
        int m = idx >> 6, d = idx & 63;
        float v = ored[d * 17 + m] + ored[(64 + d) * 17 + m] +
                  ored[(128 + d) * 17 + m] + ored[(192 + d) * 17 + m];
        outO[(int64_t)(m0 + m) * NN + hh * DD + d] = v;
    }
}

extern "C" void kernel_launch(void* const* d_in, const int* in_sizes, int n_in,
                              void* d_out, int out_size, void* d_ws, size_t ws_size,
                              hipStream_t stream) {
    const float* X  = (const float*)d_in[0];
    const float* Wq = (const float*)d_in[1];
    const float* Wk = (const float*)d_in[2];
    const float* Wv = (const float*)d_in[3];
    const float* cK = (const float*)d_in[4];
    const float* cV = (const float*)d_in[5];
    const float* nz = (const float*)d_in[6];

    char* ws = (char*)d_ws;
    const int64_t U = 1 << 21;   // 2 MB units
    unsigned short* Xh    = (unsigned short*)(ws + 0 * U);
    unsigned short* Xl    = (unsigned short*)(ws + 1 * U);
    unsigned short* WhT   = (unsigned short*)(ws + 2 * U);   // 3 units
    unsigned short* WlT   = (unsigned short*)(ws + 5 * U);   // 3 units
    unsigned short* Qh    = (unsigned short*)(ws + 8 * U);
    unsigned short* Ql    = (unsigned short*)(ws + 9 * U);
    unsigned short* Kall  = (unsigned short*)(ws + 10 * U);  // 5 units
    unsigned short* Vproj = (unsigned short*)(ws + 15 * U);
    unsigned short* VT    = (unsigned short*)(ws + 16 * U);  // 5 units

    float* outO = (float*)d_out;
    float* outW = outO + (int64_t)MM * NN;
    float* outP = outW + (int64_t)HH * MM * LL;

    k_prep<<<2048, 256, 0, stream>>>(X, cK, Xh, Xl, Kall);
    k_transW<<<dim3(16, 16, 3), 256, 0, stream>>>(Wq, Wk, Wv, WhT, WlT);
    k_gemm<<<dim3(16, 16, 3), 256, 0, stream>>>(Xh, Xl, WhT, WlT, Qh, Ql, Kall, Vproj);
    k_transV<<<1280, 256, 0, stream>>>(cV, Vproj, VT);
    k_attn2<<<1024, 256, 0, stream>>>(Qh, Ql, Kall, VT, nz, outO, outW, outP);
}